// Round 3
// baseline (16.675 us; speedup 1.0000x reference)
//
#include <hip/hip_runtime.h>

// StreamingSTFT with no spectral processing: irfft(rfft(x)) == x, so the whole
// analyze->synthesize->OLA scan collapses to
//   out[i][t] = chunk[i-3][t] * W[t]   (i >= 3; zero otherwise)
// where W[t] = aw[t+128]*sw[t+128] (t<32) else aw[t+64]*sw[t+64]  (sw is
// pad(sqrt_hann(64),(96,96)), nonzero only on [96,160)).
// In float4 units: out4[g] = chunk4[g-48] * W4[g & 15]  (g >= 48).
//
// Round-2 structure: one float4 per thread, exactly full-occupancy grid
// (8192 blocks x 256 = 2,097,152 threads = 32 blocks/CU), no grid-stride
// loop -> max memory-level parallelism; nontemporal stores keep the 32 MB
// write stream out of L2/L3 so chunk stays cache-resident across replays.

typedef float f32x4 __attribute__((ext_vector_type(4)));

#define HOP        64
#define NUM_FRAMES 131072

__global__ __launch_bounds__(256) void
StreamingSTFT_56951266345124_kernel(const f32x4* __restrict__ chunk4,
                                    const float* __restrict__ aw,
                                    const float* __restrict__ sw,
                                    f32x4* __restrict__ out4) {
    const int g = blockIdx.x * 256 + threadIdx.x;    // 0 .. 2,097,151
    const int t = (g & 15) * 4;                      // column in {0,4,...,60}
    const int n = t + ((t < 32) ? 128 : 64);         // the single nonzero window term

    const f32x4 a4 = *reinterpret_cast<const f32x4*>(aw + n);
    const f32x4 s4 = *reinterpret_cast<const f32x4*>(sw + n);
    const f32x4 w  = a4 * s4;

    f32x4 r = (f32x4)0.f;
    if (g >= 48) {                                   // false only for first 3 frames
        r = __builtin_nontemporal_load(chunk4 + (g - 48)) * w;
    }
    __builtin_nontemporal_store(r, out4 + g);
}

extern "C" void kernel_launch(void* const* d_in, const int* in_sizes, int n_in,
                              void* d_out, int out_size, void* d_ws, size_t ws_size,
                              hipStream_t stream) {
    const float* chunk = (const float*)d_in[0];
    const float* aw    = (const float*)d_in[1];
    const float* sw    = (const float*)d_in[2];
    float* out         = (float*)d_out;

    // 2,097,152 float4s, one per thread; 8192 blocks = 32 blocks/CU (full
    // occupancy, single co-resident pass, no tail).
    StreamingSTFT_56951266345124_kernel<<<8192, 256, 0, stream>>>(
        (const f32x4*)chunk, aw, sw, (f32x4*)out);
}

// Round 4
// 15.472 us; speedup vs baseline: 1.0777x; 1.0777x over previous
//
#include <hip/hip_runtime.h>

// StreamingSTFT with no spectral processing: irfft(rfft(x)) == x, so the whole
// analyze->synthesize->OLA scan collapses to
//   out[i][t] = chunk[i-3][t] * W[t]   (i >= 3; zero otherwise)
// where W[t] = aw[t+128]*sw[t+128] (t<32) else aw[t+64]*sw[t+64]  (sw is
// pad(sqrt_hann(64),(96,96)), nonzero only on [96,160)).
// In float4 units: out4[g] = chunk4[g-48] * W4[g & 15]  (g >= 48).
//
// Round-3: round-2's max-MLP structure (one float4 per thread, exactly
// full-occupancy 8192x256 grid, no loop, single load->mul->store chain) but
// with PLAIN cached accesses: both buffers (32+32 MB) fit in the 256 MB L3
// and the harness replays the graph without touching them, so cached
// loads AND stores keep the whole working set Infinity-Cache-resident
// (round 2's nontemporal hints forced HBM traffic and cost +0.75 us).

typedef float f32x4 __attribute__((ext_vector_type(4)));

#define HOP        64
#define NUM_FRAMES 131072

__global__ __launch_bounds__(256) void
StreamingSTFT_56951266345124_kernel(const f32x4* __restrict__ chunk4,
                                    const float* __restrict__ aw,
                                    const float* __restrict__ sw,
                                    f32x4* __restrict__ out4) {
    const int g = blockIdx.x * 256 + threadIdx.x;    // 0 .. 2,097,151
    const int t = (g & 15) * 4;                      // column in {0,4,...,60}
    const int n = t + ((t < 32) ? 128 : 64);         // the single nonzero window term

    const f32x4 a4 = *reinterpret_cast<const f32x4*>(aw + n);
    const f32x4 s4 = *reinterpret_cast<const f32x4*>(sw + n);
    const f32x4 w  = a4 * s4;

    f32x4 r = (f32x4)0.f;
    if (g >= 48) {                                   // false only for first 3 frames
        r = chunk4[g - 48] * w;
    }
    out4[g] = r;
}

extern "C" void kernel_launch(void* const* d_in, const int* in_sizes, int n_in,
                              void* d_out, int out_size, void* d_ws, size_t ws_size,
                              hipStream_t stream) {
    const float* chunk = (const float*)d_in[0];
    const float* aw    = (const float*)d_in[1];
    const float* sw    = (const float*)d_in[2];
    float* out         = (float*)d_out;

    // 2,097,152 float4s, one per thread; 8192 blocks = 32 blocks/CU (full
    // occupancy, single co-resident pass, no tail).
    StreamingSTFT_56951266345124_kernel<<<8192, 256, 0, stream>>>(
        (const f32x4*)chunk, aw, sw, (f32x4*)out);
}